// Round 9
// baseline (530.494 us; speedup 1.0000x reference)
//
#include <hip/hip_runtime.h>
#include <hip/hip_fp16.h>

#define N_NODES 50000
#define N_EDGES 800000
#define DIM_IN 128
#define DIM_H 256

typedef _Float16 f16;
typedef _Float16 half8 __attribute__((ext_vector_type(8)));
typedef _Float16 f16x4 __attribute__((ext_vector_type(4)));
typedef _Float16 f16x2 __attribute__((ext_vector_type(2)));
typedef float f32x4 __attribute__((ext_vector_type(4)));
typedef unsigned int u32;

__device__ __forceinline__ void gload_lds16(const void* g, void* l) {
    __builtin_amdgcn_global_load_lds(
        (const __attribute__((address_space(1))) u32*)g,
        (__attribute__((address_space(3))) u32*)l,
        16, 0, 0);
}

// ---------------- graph build ----------------

__global__ void k_scan1(const int* __restrict__ deg, int* __restrict__ row_start,
                        int* __restrict__ partials) {
    __shared__ int sm[256];
    int t = threadIdx.x;
    int i = blockIdx.x * 256 + t;
    int v = (i < N_NODES) ? deg[i] : 0;
    sm[t] = v;
    __syncthreads();
    for (int ofs = 1; ofs < 256; ofs <<= 1) {
        int add = (t >= ofs) ? sm[t - ofs] : 0;
        __syncthreads();
        sm[t] += add;
        __syncthreads();
    }
    if (i < N_NODES) row_start[i] = sm[t] - v;   // exclusive
    if (t == 255) partials[blockIdx.x] = sm[255];
}

__global__ void k_scan2(const int* __restrict__ partials, int* __restrict__ pscan, int nblk) {
    __shared__ int sm[256];
    int t = threadIdx.x;
    int v = (t < nblk) ? partials[t] : 0;
    sm[t] = v;
    __syncthreads();
    for (int ofs = 1; ofs < 256; ofs <<= 1) {
        int add = (t >= ofs) ? sm[t - ofs] : 0;
        __syncthreads();
        sm[t] += add;
        __syncthreads();
    }
    pscan[t] = sm[t] - v;  // exclusive
}

__global__ void k_scan3(const int* __restrict__ deg, int* __restrict__ row_start,
                        const int* __restrict__ pscan, float* __restrict__ inv_deg) {
    int i = blockIdx.x * 256 + threadIdx.x;
    if (i < N_NODES) {
        row_start[i] += pscan[blockIdx.x];
        int d = deg[i];
        inv_deg[i] = 1.0f / (float)(d > 1 ? d : 1);
        if (i == 0) row_start[N_NODES] = N_EDGES;
    }
}

__global__ void k_fill(const int* __restrict__ src, const int* __restrict__ dst,
                       const int* __restrict__ row_start, int* __restrict__ cursor,
                       int* __restrict__ csr) {
    int i = blockIdx.x * 256 + threadIdx.x;
    if (i < N_EDGES) {
        int d = dst[i];
        int p = atomicAdd(&cursor[d], 1);
        csr[row_start[d] + p] = src[i];
    }
}

// ---------------- fused prep: cvt_x + 7 tcvt + st + deg histogram ----------------
// blockIdx segments:
//   [0,6250)      cvt_x (1.6M float4)
//   [6250,6378)   tcvt wn0  (K=128)
//   [6378,6506)   tcvt wr0  (K=128)
//   [6506,6762)   tcvt wn1
//   [6762,7018)   tcvt wn2
//   [7018,7274)   tcvt wr1
//   [7274,7530)   tcvt wr2
//   [7530,7658)   tcvt w1   (K=256,N=128)
//   7658          st (BN fold)
//   [7659,10784)  deg atomics (deg pre-zeroed by memsetAsync)

__global__ void k_prep(const float* __restrict__ x, f16* __restrict__ hA,
                       const float* __restrict__ wn0, f16* __restrict__ Wn0t,
                       const float* __restrict__ wr0, f16* __restrict__ Wr0t,
                       const float* __restrict__ wn12, f16* __restrict__ Wn1t,
                       f16* __restrict__ Wn2t,
                       const float* __restrict__ wr12, f16* __restrict__ Wr1t,
                       f16* __restrict__ Wr2t,
                       const float* __restrict__ w1, f16* __restrict__ W1t,
                       const float* __restrict__ b0, const float* __restrict__ bvec,
                       const float* __restrict__ gamma, const float* __restrict__ beta,
                       const float* __restrict__ mean, const float* __restrict__ var,
                       const float* __restrict__ b1, float* __restrict__ st,
                       const int* __restrict__ dst, int* __restrict__ deg) {
    const int t = threadIdx.x;
    int b = blockIdx.x;
    auto tcvt = [&](const float* W, f16* Wt, int K, int NN, int bb) {
        int tt = bb * 256 + t;
        int n = tt / K, k = tt - n * K;
        Wt[tt] = (f16)W[(size_t)k * NN + n];
    };
    if (b < 6250) {
        int i = b * 256 + t;   // < 1.6M exactly
        float4 v = ((const float4*)x)[i];
        f16x4 h = {(f16)v.x, (f16)v.y, (f16)v.z, (f16)v.w};
        *(f16x4*)(hA + (size_t)i * 4) = h;
    } else if (b < 6378) {
        tcvt(wn0, Wn0t, 128, 256, b - 6250);
    } else if (b < 6506) {
        tcvt(wr0, Wr0t, 128, 256, b - 6378);
    } else if (b < 6762) {
        tcvt(wn12, Wn1t, 256, 256, b - 6506);
    } else if (b < 7018) {
        tcvt(wn12 + 65536, Wn2t, 256, 256, b - 6762);
    } else if (b < 7274) {
        tcvt(wr12, Wr1t, 256, 256, b - 7018);
    } else if (b < 7530) {
        tcvt(wr12 + 65536, Wr2t, 256, 256, b - 7274);
    } else if (b < 7658) {
        tcvt(w1, W1t, 256, 128, b - 7530);
    } else if (b == 7658) {
        int c = t;
        for (int layer = 0; layer < 3; layer++) {
            float bias = (layer == 0) ? b0[c] : bvec[(layer - 1) * DIM_H + c];
            float g = gamma[layer * DIM_H + c];
            float be = beta[layer * DIM_H + c];
            float mu = mean[layer * DIM_H + c];
            float va = var[layer * DIM_H + c];
            float s = g * rsqrtf(va + 1e-5f);
            st[layer * 512 + c] = s;
            st[layer * 512 + 256 + c] = (bias - mu) * s + be;
        }
        st[3 * 512 + c] = 1.0f;
        st[3 * 512 + 256 + c] = (c < 128) ? b1[c] : 0.0f;
    } else {
        int i = (b - 7659) * 256 + t;
        if (i < N_EDGES) atomicAdd(&deg[dst[i]], 1);
    }
}

// ---------------- fused agg + root-GEMM ----------------
// Blocks [0,ngemm): Croot[m0..m0+64) = h @ Wr^T (raw f16 accum, BM=64 x BN=256).
// Blocks [ngemm,..): R2-proven agg (one wave per node, 16 gathers in flight).
// Both roles only READ h; Croot aliases the layer's output buffer (dead data).

template <int D>
__global__ __launch_bounds__(256) void k_fused(
    const f16* __restrict__ h, const int* __restrict__ row_start,
    const int* __restrict__ csr, const float* __restrict__ inv_deg,
    f16* __restrict__ agg,
    const f16* __restrict__ Wr,     // [256][D] pre-transposed
    f16* __restrict__ Croot,        // [N][256]
    int ngemm) {
    __shared__ f16 aT[2][64 * 32];
    __shared__ f16 bT[2][256 * 32];
    const int tid = threadIdx.x;
    const int lane = tid & 63;
    const int wid = tid >> 6;

    if ((int)blockIdx.x < ngemm) {
        const int m0 = blockIdx.x * 64;
        f32x4 acc[4][4] = {};
        const int srow = tid >> 2;
        const int schunk = (tid & 3) ^ ((tid >> 3) & 3);

        auto stage = [&](int buf, int kk) {
            int gm = m0 + srow;
            gm = gm < N_NODES ? gm : N_NODES - 1;
            gload_lds16(h + (size_t)gm * D + kk + schunk * 8,
                        (char*)&aT[buf][0] + tid * 16);
#pragma unroll
            for (int hh = 0; hh < 4; hh++) {
                gload_lds16(Wr + (size_t)(hh * 64 + srow) * D + kk + schunk * 8,
                            (char*)&bT[buf][0] + hh * 4096 + tid * 16);
            }
        };
        auto compute = [&](int buf) {
            half8 af[4], bf[4];
#pragma unroll
            for (int mi = 0; mi < 4; mi++) {
                int row = mi * 16 + (lane & 15);
                int ch = (lane >> 4) ^ ((row >> 1) & 3);
                af[mi] = *(const half8*)((const char*)&aT[buf][0] + row * 64 + ch * 16);
            }
#pragma unroll
            for (int ni = 0; ni < 4; ni++) {
                int row = wid * 64 + ni * 16 + (lane & 15);
                int ch = (lane >> 4) ^ ((row >> 1) & 3);
                bf[ni] = *(const half8*)((const char*)&bT[buf][0] + row * 64 + ch * 16);
            }
#pragma unroll
            for (int mi = 0; mi < 4; mi++)
#pragma unroll
                for (int ni = 0; ni < 4; ni++)
                    acc[mi][ni] = __builtin_amdgcn_mfma_f32_16x16x32_f16(af[mi], bf[ni],
                                                                         acc[mi][ni], 0, 0, 0);
        };

        stage(0, 0);
        __syncthreads();
        int cur = 0;
        for (int kk = 32; kk < D; kk += 32) {
            stage(cur ^ 1, kk);
            compute(cur);
            __syncthreads();
            cur ^= 1;
        }
        compute(cur);

#pragma unroll
        for (int mi = 0; mi < 4; mi++) {
#pragma unroll
            for (int ni = 0; ni < 4; ni++) {
                int gcol = wid * 64 + ni * 16 + (lane & 15);
#pragma unroll
                for (int r = 0; r < 4; r++) {
                    int grow = m0 + mi * 16 + (lane >> 4) * 4 + r;
                    if (grow < N_NODES)
                        Croot[(size_t)grow * 256 + gcol] = (f16)acc[mi][ni][r];
                }
            }
        }
    } else {
        constexpr int V = D / 64;
        typedef _Float16 fvec __attribute__((ext_vector_type(V)));
        int v = (blockIdx.x - ngemm) * 4 + wid;
        if (v >= N_NODES) return;
        int e0 = row_start[v], e1 = row_start[v + 1];
        float acc[V];
#pragma unroll
        for (int j = 0; j < V; j++) acc[j] = 0.0f;

        const int li = lane & 15;
        for (int e = e0; e < e1; e += 16) {
            int ee = e + li;
            int idx = csr[ee < e1 ? ee : e1 - 1];
            int rem = e1 - e;
            fvec hv[16];
#pragma unroll
            for (int j = 0; j < 16; j++) {
                int s = __shfl(idx, j);
                hv[j] = *(const fvec*)(h + (size_t)s * D + lane * V);
            }
#pragma unroll
            for (int j = 0; j < 16; j++) {
                if (j < rem) {
#pragma unroll
                    for (int q = 0; q < V; q++) acc[q] += (float)hv[j][q];
                }
            }
        }

        float sc = inv_deg[v];
        fvec o;
#pragma unroll
        for (int j = 0; j < V; j++) o[j] = (f16)(acc[j] * sc);
        *(fvec*)(agg + (size_t)v * D + lane * V) = o;
    }
}

// ---------------- nei-GEMM: out = relu(sc * (agg@Wn^T + Croot) + sh) -------------
// Croot MAY ALIAS out (same element, same thread: read-then-write) -> no restrict.

__global__ __launch_bounds__(256) void k_gemm_nei(
    const f16* __restrict__ A1, int k1, const f16* __restrict__ B1,
    const f16* Croot,
    const float* __restrict__ sc, const float* __restrict__ sh,
    f16* out, int M) {
    __shared__ f16 aT[2][64 * 32];
    __shared__ f16 bT[2][256 * 32];
    const int tid = threadIdx.x;
    const int lane = tid & 63;
    const int wid = tid >> 6;
    const int m0 = blockIdx.x * 64;
    f32x4 acc[4][4] = {};

    const int srow = tid >> 2;
    const int schunk = (tid & 3) ^ ((tid >> 3) & 3);

    auto stage = [&](int buf, int kk) {
        int gm = m0 + srow;
        gm = gm < M ? gm : M - 1;
        gload_lds16(A1 + (size_t)gm * k1 + kk + schunk * 8,
                    (char*)&aT[buf][0] + tid * 16);
#pragma unroll
        for (int hh = 0; hh < 4; hh++) {
            gload_lds16(B1 + (size_t)(hh * 64 + srow) * k1 + kk + schunk * 8,
                        (char*)&bT[buf][0] + hh * 4096 + tid * 16);
        }
    };
    auto compute = [&](int buf) {
        half8 af[4], bf[4];
#pragma unroll
        for (int mi = 0; mi < 4; mi++) {
            int row = mi * 16 + (lane & 15);
            int ch = (lane >> 4) ^ ((row >> 1) & 3);
            af[mi] = *(const half8*)((const char*)&aT[buf][0] + row * 64 + ch * 16);
        }
#pragma unroll
        for (int ni = 0; ni < 4; ni++) {
            int row = wid * 64 + ni * 16 + (lane & 15);
            int ch = (lane >> 4) ^ ((row >> 1) & 3);
            bf[ni] = *(const half8*)((const char*)&bT[buf][0] + row * 64 + ch * 16);
        }
#pragma unroll
        for (int mi = 0; mi < 4; mi++)
#pragma unroll
            for (int ni = 0; ni < 4; ni++)
                acc[mi][ni] = __builtin_amdgcn_mfma_f32_16x16x32_f16(af[mi], bf[ni],
                                                                     acc[mi][ni], 0, 0, 0);
    };

    stage(0, 0);
    __syncthreads();
    int cur = 0;
    for (int kk = 32; kk < k1; kk += 32) {
        stage(cur ^ 1, kk);
        compute(cur);
        __syncthreads();
        cur ^= 1;
    }
    compute(cur);

#pragma unroll
    for (int mi = 0; mi < 4; mi++) {
#pragma unroll
        for (int ni = 0; ni < 4; ni++) {
            int gcol = wid * 64 + ni * 16 + (lane & 15);
            float s = sc[gcol], t = sh[gcol];
#pragma unroll
            for (int r = 0; r < 4; r++) {
                int grow = m0 + mi * 16 + (lane >> 4) * 4 + r;
                if (grow < M) {
                    float cr = (float)Croot[(size_t)grow * 256 + gcol];
                    float val = fmaxf((acc[mi][ni][r] + cr) * s + t, 0.0f);
                    out[(size_t)grow * 256 + gcol] = (f16)val;
                }
            }
        }
    }
}

// ---------------- head: fc1(relu) GEMM with fused fc2 + log_softmax epilogue ----------

__global__ __launch_bounds__(256) void k_gemm_head(
    const f16* __restrict__ A1, int k1, const f16* __restrict__ B1,
    const float* __restrict__ sh,
    const float* __restrict__ w2, const float* __restrict__ b2,
    float* __restrict__ out, int M) {
    __shared__ f16 aT[2][128 * 32];
    __shared__ f16 bT[2][128 * 32];
    __shared__ float smred[128][2][2];
    const int tid = threadIdx.x;
    const int lane = tid & 63;
    const int wid = tid >> 6;
    const int wm = wid >> 1, wn = wid & 1;
    const int m0 = blockIdx.x * 128;
    f32x4 acc[4][4] = {};

    const int srow = tid >> 2;
    const int schunk = (tid & 3) ^ ((tid >> 3) & 3);

    auto stage = [&](int buf, int kk) {
#pragma unroll
        for (int hh = 0; hh < 2; hh++) {
            int r = hh * 64 + srow;
            int gm = m0 + r;
            gm = gm < M ? gm : M - 1;
            gload_lds16(A1 + (size_t)gm * k1 + kk + schunk * 8,
                        (char*)&aT[buf][0] + hh * 4096 + tid * 16);
            gload_lds16(B1 + (size_t)r * k1 + kk + schunk * 8,
                        (char*)&bT[buf][0] + hh * 4096 + tid * 16);
        }
    };

    auto compute = [&](int buf) {
        half8 af[4], bf[4];
#pragma unroll
        for (int mi = 0; mi < 4; mi++) {
            int row = wm * 64 + mi * 16 + (lane & 15);
            int ch = (lane >> 4) ^ ((row >> 1) & 3);
            af[mi] = *(const half8*)((const char*)&aT[buf][0] + row * 64 + ch * 16);
        }
#pragma unroll
        for (int ni = 0; ni < 4; ni++) {
            int row = wn * 64 + ni * 16 + (lane & 15);
            int ch = (lane >> 4) ^ ((row >> 1) & 3);
            bf[ni] = *(const half8*)((const char*)&bT[buf][0] + row * 64 + ch * 16);
        }
#pragma unroll
        for (int mi = 0; mi < 4; mi++)
#pragma unroll
            for (int ni = 0; ni < 4; ni++)
                acc[mi][ni] = __builtin_amdgcn_mfma_f32_16x16x32_f16(af[mi], bf[ni],
                                                                     acc[mi][ni], 0, 0, 0);
    };

    stage(0, 0);
    __syncthreads();
    int cur = 0;
    for (int kk = 32; kk < k1; kk += 32) {
        stage(cur ^ 1, kk);
        compute(cur);
        __syncthreads();
        cur ^= 1;
    }
    compute(cur);

    // fused epilogue: relu(acc + b1) @ w2  -> log_softmax
    float w2c[4][2], shc[4];
#pragma unroll
    for (int ni = 0; ni < 4; ni++) {
        int c = wn * 64 + ni * 16 + (lane & 15);
        w2c[ni][0] = w2[c * 2];
        w2c[ni][1] = w2[c * 2 + 1];
        shc[ni] = sh[c];
    }
#pragma unroll
    for (int mi = 0; mi < 4; mi++) {
#pragma unroll
        for (int r = 0; r < 4; r++) {
            float p0 = 0.0f, p1 = 0.0f;
#pragma unroll
            for (int ni = 0; ni < 4; ni++) {
                float val = fmaxf(acc[mi][ni][r] + shc[ni], 0.0f);
                p0 += val * w2c[ni][0];
                p1 += val * w2c[ni][1];
            }
#pragma unroll
            for (int o = 1; o < 16; o <<= 1) {
                p0 += __shfl_xor(p0, o);
                p1 += __shfl_xor(p1, o);
            }
            if ((lane & 15) == 0) {
                int lrow = wm * 64 + mi * 16 + (lane >> 4) * 4 + r;
                smred[lrow][wn][0] = p0;
                smred[lrow][wn][1] = p1;
            }
        }
    }
    __syncthreads();
    if (tid < 128) {
        int grow = m0 + tid;
        if (grow < M) {
            float l0 = smred[tid][0][0] + smred[tid][1][0] + b2[0];
            float l1 = smred[tid][0][1] + smred[tid][1][1] + b2[1];
            float m = fmaxf(l0, l1);
            float lse = m + logf(expf(l0 - m) + expf(l1 - m));
            out[(size_t)grow * 2] = l0 - lse;
            out[(size_t)grow * 2 + 1] = l1 - lse;
        }
    }
}

// ---------------- launch ----------------

extern "C" void kernel_launch(void* const* d_in, const int* in_sizes, int n_in,
                              void* d_out, int out_size, void* d_ws, size_t ws_size,
                              hipStream_t stream) {
    const float* x     = (const float*)d_in[0];
    const int*   ei    = (const int*)d_in[1];
    const float* wn0   = (const float*)d_in[2];
    const float* wr0   = (const float*)d_in[3];
    const float* b0    = (const float*)d_in[4];
    const float* wn12  = (const float*)d_in[5];
    const float* wr12  = (const float*)d_in[6];
    const float* bvec  = (const float*)d_in[7];
    const float* gamma = (const float*)d_in[8];
    const float* beta  = (const float*)d_in[9];
    const float* mean  = (const float*)d_in[10];
    const float* var   = (const float*)d_in[11];
    const float* w1    = (const float*)d_in[12];
    const float* b1    = (const float*)d_in[13];
    const float* w2    = (const float*)d_in[14];
    const float* b2    = (const float*)d_in[15];
    const int* srcv = ei;
    const int* dstv = ei + N_EDGES;

    char* p = (char*)d_ws;
    auto alloc = [&](size_t bytes) {
        char* r = p;
        p += (bytes + 255) & ~(size_t)255;
        return r;
    };
    int*   deg       = (int*)alloc((size_t)N_NODES * 4);
    int*   row_start = (int*)alloc((size_t)(N_NODES + 1) * 4);
    int*   cursor    = (int*)alloc((size_t)N_NODES * 4);
    float* inv_deg   = (float*)alloc((size_t)N_NODES * 4);
    int*   partials  = (int*)alloc(256 * 4);
    int*   pscan     = (int*)alloc(256 * 4);
    int*   csr       = (int*)alloc((size_t)N_EDGES * 4);
    f16*   Wn0t      = (f16*)alloc(128 * 256 * 2);
    f16*   Wr0t      = (f16*)alloc(128 * 256 * 2);
    f16*   Wn1t      = (f16*)alloc(256 * 256 * 2);
    f16*   Wr1t      = (f16*)alloc(256 * 256 * 2);
    f16*   Wn2t      = (f16*)alloc(256 * 256 * 2);
    f16*   Wr2t      = (f16*)alloc(256 * 256 * 2);
    f16*   W1t       = (f16*)alloc(256 * 128 * 2);
    float* st        = (float*)alloc(4 * 512 * 4);
    f16*   hA        = (f16*)alloc((size_t)N_NODES * 256 * 2);
    f16*   hB        = (f16*)alloc((size_t)N_NODES * 256 * 2);
    f16*   agg       = (f16*)alloc((size_t)N_NODES * 256 * 2);

    hipMemsetAsync(deg, 0, (size_t)N_NODES * 4, stream);
    hipMemsetAsync(cursor, 0, (size_t)N_NODES * 4, stream);

    const int EB = (N_EDGES + 255) / 256;
    const int NBLK = (N_NODES + 255) / 256;

    // fused prep (cvt + weight transposes + BN fold + deg histogram)
    k_prep<<<10784, 256, 0, stream>>>(x, hA, wn0, Wn0t, wr0, Wr0t,
                                      wn12, Wn1t, Wn2t, wr12, Wr1t, Wr2t,
                                      w1, W1t, b0, bvec, gamma, beta, mean, var,
                                      b1, st, dstv, deg);
    k_scan1<<<NBLK, 256, 0, stream>>>(deg, row_start, partials);
    k_scan2<<<1, 256, 0, stream>>>(partials, pscan, NBLK);
    k_scan3<<<NBLK, 256, 0, stream>>>(deg, row_start, pscan, inv_deg);
    k_fill<<<EB, 256, 0, stream>>>(srcv, dstv, row_start, cursor, csr);

    const int AB = (N_NODES + 3) / 4;          // agg blocks (4 nodes/block)
    const int GB = (N_NODES + 63) / 64;        // gemm blocks (64 rows/block)

    // layer 0: fused(agg<128> + root-gemm K=128 -> Croot=hB), then nei -> hB
    k_fused<128><<<GB + AB, 256, 0, stream>>>(hA, row_start, csr, inv_deg, agg,
                                              Wr0t, hB, GB);
    k_gemm_nei<<<GB, 256, 0, stream>>>(agg, 128, Wn0t, hB, st + 0, st + 256,
                                       hB, N_NODES);
    // layer 1: h=hB -> Croot=hA, out=hA
    k_fused<256><<<GB + AB, 256, 0, stream>>>(hB, row_start, csr, inv_deg, agg,
                                              Wr1t, hA, GB);
    k_gemm_nei<<<GB, 256, 0, stream>>>(agg, 256, Wn1t, hA, st + 512, st + 768,
                                       hA, N_NODES);
    // layer 2: h=hA -> Croot=hB, out=hB
    k_fused<256><<<GB + AB, 256, 0, stream>>>(hA, row_start, csr, inv_deg, agg,
                                              Wr2t, hB, GB);
    k_gemm_nei<<<GB, 256, 0, stream>>>(agg, 256, Wn2t, hB, st + 1024, st + 1280,
                                       hB, N_NODES);
    // head: fc1 + relu + fc2 + log_softmax fused
    k_gemm_head<<<(N_NODES + 127) / 128, 256, 0, stream>>>(
        hB, 256, W1t, st + 1792, w2, b2, (float*)d_out, N_NODES);
}

// Round 10
// 334.655 us; speedup vs baseline: 1.5852x; 1.5852x over previous
//
#include <hip/hip_runtime.h>
#include <hip/hip_fp16.h>

#define N_NODES 50000
#define N_EDGES 800000
#define DIM_IN 128
#define DIM_H 256

typedef _Float16 f16;
typedef _Float16 half8 __attribute__((ext_vector_type(8)));
typedef _Float16 f16x4 __attribute__((ext_vector_type(4)));
typedef _Float16 f16x2 __attribute__((ext_vector_type(2)));
typedef float f32x4 __attribute__((ext_vector_type(4)));
typedef unsigned int u32;

__device__ __forceinline__ void gload_lds16(const void* g, void* l) {
    __builtin_amdgcn_global_load_lds(
        (const __attribute__((address_space(1))) u32*)g,
        (__attribute__((address_space(3))) u32*)l,
        16, 0, 0);
}

// ---------------- graph build ----------------

__global__ void k_scan1(const int* __restrict__ deg, int* __restrict__ row_start,
                        int* __restrict__ partials) {
    __shared__ int sm[256];
    int t = threadIdx.x;
    int i = blockIdx.x * 256 + t;
    int v = (i < N_NODES) ? deg[i] : 0;
    sm[t] = v;
    __syncthreads();
    for (int ofs = 1; ofs < 256; ofs <<= 1) {
        int add = (t >= ofs) ? sm[t - ofs] : 0;
        __syncthreads();
        sm[t] += add;
        __syncthreads();
    }
    if (i < N_NODES) row_start[i] = sm[t] - v;   // exclusive
    if (t == 255) partials[blockIdx.x] = sm[255];
}

__global__ void k_scan2(const int* __restrict__ partials, int* __restrict__ pscan, int nblk) {
    __shared__ int sm[256];
    int t = threadIdx.x;
    int v = (t < nblk) ? partials[t] : 0;
    sm[t] = v;
    __syncthreads();
    for (int ofs = 1; ofs < 256; ofs <<= 1) {
        int add = (t >= ofs) ? sm[t - ofs] : 0;
        __syncthreads();
        sm[t] += add;
        __syncthreads();
    }
    pscan[t] = sm[t] - v;  // exclusive
}

__global__ void k_scan3(const int* __restrict__ deg, int* __restrict__ row_start,
                        const int* __restrict__ pscan, float* __restrict__ inv_deg) {
    int i = blockIdx.x * 256 + threadIdx.x;
    if (i < N_NODES) {
        row_start[i] += pscan[blockIdx.x];
        int d = deg[i];
        inv_deg[i] = 1.0f / (float)(d > 1 ? d : 1);
        if (i == 0) row_start[N_NODES] = N_EDGES;
    }
}

__global__ void k_fill(const int* __restrict__ src, const int* __restrict__ dst,
                       const int* __restrict__ row_start, int* __restrict__ cursor,
                       int* __restrict__ csr) {
    int i = blockIdx.x * 256 + threadIdx.x;
    if (i < N_EDGES) {
        int d = dst[i];
        int p = atomicAdd(&cursor[d], 1);
        csr[row_start[d] + p] = src[i];
    }
}

// ---------------- fused prep: cvt_x + 7 tcvt + st + deg histogram ----------------

__global__ void k_prep(const float* __restrict__ x, f16* __restrict__ hA,
                       const float* __restrict__ wn0, f16* __restrict__ Wn0t,
                       const float* __restrict__ wr0, f16* __restrict__ Wr0t,
                       const float* __restrict__ wn12, f16* __restrict__ Wn1t,
                       f16* __restrict__ Wn2t,
                       const float* __restrict__ wr12, f16* __restrict__ Wr1t,
                       f16* __restrict__ Wr2t,
                       const float* __restrict__ w1, f16* __restrict__ W1t,
                       const float* __restrict__ b0, const float* __restrict__ bvec,
                       const float* __restrict__ gamma, const float* __restrict__ beta,
                       const float* __restrict__ mean, const float* __restrict__ var,
                       const float* __restrict__ b1, float* __restrict__ st,
                       const int* __restrict__ dst, int* __restrict__ deg) {
    const int t = threadIdx.x;
    int b = blockIdx.x;
    auto tcvt = [&](const float* W, f16* Wt, int K, int NN, int bb) {
        int tt = bb * 256 + t;
        int n = tt / K, k = tt - n * K;
        Wt[tt] = (f16)W[(size_t)k * NN + n];
    };
    if (b < 6250) {
        int i = b * 256 + t;   // < 1.6M exactly
        float4 v = ((const float4*)x)[i];
        f16x4 h = {(f16)v.x, (f16)v.y, (f16)v.z, (f16)v.w};
        *(f16x4*)(hA + (size_t)i * 4) = h;
    } else if (b < 6378) {
        tcvt(wn0, Wn0t, 128, 256, b - 6250);
    } else if (b < 6506) {
        tcvt(wr0, Wr0t, 128, 256, b - 6378);
    } else if (b < 6762) {
        tcvt(wn12, Wn1t, 256, 256, b - 6506);
    } else if (b < 7018) {
        tcvt(wn12 + 65536, Wn2t, 256, 256, b - 6762);
    } else if (b < 7274) {
        tcvt(wr12, Wr1t, 256, 256, b - 7018);
    } else if (b < 7530) {
        tcvt(wr12 + 65536, Wr2t, 256, 256, b - 7274);
    } else if (b < 7658) {
        tcvt(w1, W1t, 256, 128, b - 7530);
    } else if (b == 7658) {
        int c = t;
        for (int layer = 0; layer < 3; layer++) {
            float bias = (layer == 0) ? b0[c] : bvec[(layer - 1) * DIM_H + c];
            float g = gamma[layer * DIM_H + c];
            float be = beta[layer * DIM_H + c];
            float mu = mean[layer * DIM_H + c];
            float va = var[layer * DIM_H + c];
            float s = g * rsqrtf(va + 1e-5f);
            st[layer * 512 + c] = s;
            st[layer * 512 + 256 + c] = (bias - mu) * s + be;
        }
        st[3 * 512 + c] = 1.0f;
        st[3 * 512 + 256 + c] = (c < 128) ? b1[c] : 0.0f;
    } else {
        int i = (b - 7659) * 256 + t;
        if (i < N_EDGES) atomicAdd(&deg[dst[i]], 1);
    }
}

// ---------------- aggregation: one wave per node, 16 gathers in flight (R2 proven) ----

template <int D>
__global__ void k_agg(const f16* __restrict__ h, const int* __restrict__ row_start,
                      const int* __restrict__ csr, const float* __restrict__ inv_deg,
                      f16* __restrict__ agg) {
    constexpr int V = D / 64;  // halves per lane: 2 or 4
    typedef _Float16 fvec __attribute__((ext_vector_type(V)));
    int wid = threadIdx.x >> 6;
    int lane = threadIdx.x & 63;
    int v = blockIdx.x * 4 + wid;
    if (v >= N_NODES) return;
    int e0 = row_start[v], e1 = row_start[v + 1];
    float acc[V];
#pragma unroll
    for (int j = 0; j < V; j++) acc[j] = 0.0f;

    const int li = lane & 15;
    for (int e = e0; e < e1; e += 16) {
        int ee = e + li;
        int idx = csr[ee < e1 ? ee : e1 - 1];   // coalesced; tail lanes duplicate last
        int rem = e1 - e;                        // wave-uniform
        fvec hv[16];
#pragma unroll
        for (int j = 0; j < 16; j++) {
            int s = __shfl(idx, j);
            hv[j] = *(const fvec*)(h + (size_t)s * D + lane * V);  // 16 loads in flight
        }
#pragma unroll
        for (int j = 0; j < 16; j++) {
            if (j < rem) {  // wave-uniform scalar branch
#pragma unroll
                for (int q = 0; q < V; q++) acc[q] += (float)hv[j][q];
            }
        }
    }

    float sc = inv_deg[v];
    fvec o;
#pragma unroll
    for (int j = 0; j < V; j++) o[j] = (f16)(acc[j] * sc);
    *(fvec*)(agg + (size_t)v * D + lane * V) = o;
}

// ---------------- GEMM: C = relu(sc * (A1@B1t^T + A2@B2t^T) + sh) ----------------
// BM=128 x BN=256, 512 threads (8 waves, 2x4), each wave 64x64 (4x4 of 16x16x32).
// K-step 32, double-buffered LDS (48KB -> 2 blocks/CU = 16 waves/CU).
// Staging: 3 gload_lds16/thread/K-step (vs 5 at BM=64). Bt[n][k].

__global__ __launch_bounds__(512) void k_gemm(
    const f16* __restrict__ A1, int lda1, const f16* __restrict__ B1, int k1,
    const f16* __restrict__ A2, int lda2, const f16* __restrict__ B2, int k2,
    const float* __restrict__ sc, const float* __restrict__ sh,
    f16* __restrict__ out, int ldo, int M) {
    __shared__ f16 aT[2][128 * 32];
    __shared__ f16 bT[2][256 * 32];
    const int tid = threadIdx.x;
    const int lane = tid & 63;
    const int wid = tid >> 6;
    const int wm = wid >> 2;            // 0..1: row half
    const int wn = wid & 3;             // 0..3: col quarter
    const int m0 = blockIdx.x * 128;
    f32x4 acc[4][4] = {};

    const int srow = tid >> 2;                       // 0..127
    const int schunk = (tid & 3) ^ ((tid >> 3) & 3); // pre-swizzled global chunk
    const int ktot = k1 + k2;

    auto stage = [&](int buf, int kk) {
        const f16 *Ap, *Bp;
        int lda, ldb, kloc;
        if (kk < k1) { Ap = A1; Bp = B1; lda = lda1; ldb = k1; kloc = kk; }
        else         { Ap = A2; Bp = B2; lda = lda2; ldb = k2; kloc = kk - k1; }
        // A: 128 rows x 64B -> 1 gload per thread
        int gm = m0 + srow;
        gm = gm < M ? gm : M - 1;
        gload_lds16(Ap + (size_t)gm * lda + kloc + schunk * 8,
                    (char*)&aT[buf][0] + tid * 16);
        // B: 256 rows x 64B -> 2 gloads per thread
#pragma unroll
        for (int hh = 0; hh < 2; hh++) {
            gload_lds16(Bp + (size_t)(hh * 128 + srow) * ldb + kloc + schunk * 8,
                        (char*)&bT[buf][0] + hh * 8192 + tid * 16);
        }
    };

    auto compute = [&](int buf) {
        half8 af[4], bf[4];
#pragma unroll
        for (int mi = 0; mi < 4; mi++) {
            int row = wm * 64 + mi * 16 + (lane & 15);
            int ch = (lane >> 4) ^ ((row >> 1) & 3);
            af[mi] = *(const half8*)((const char*)&aT[buf][0] + row * 64 + ch * 16);
        }
#pragma unroll
        for (int ni = 0; ni < 4; ni++) {
            int row = wn * 64 + ni * 16 + (lane & 15);
            int ch = (lane >> 4) ^ ((row >> 1) & 3);
            bf[ni] = *(const half8*)((const char*)&bT[buf][0] + row * 64 + ch * 16);
        }
#pragma unroll
        for (int mi = 0; mi < 4; mi++)
#pragma unroll
            for (int ni = 0; ni < 4; ni++)
                acc[mi][ni] = __builtin_amdgcn_mfma_f32_16x16x32_f16(af[mi], bf[ni],
                                                                     acc[mi][ni], 0, 0, 0);
    };

    stage(0, 0);
    __syncthreads();
    int cur = 0;
    for (int kk = 32; kk < ktot; kk += 32) {
        stage(cur ^ 1, kk);
        compute(cur);
        __syncthreads();
        cur ^= 1;
    }
    compute(cur);

#pragma unroll
    for (int mi = 0; mi < 4; mi++) {
#pragma unroll
        for (int ni = 0; ni < 4; ni++) {
            int gcol = wn * 64 + ni * 16 + (lane & 15);
            float s = sc[gcol], t = sh[gcol];
#pragma unroll
            for (int r = 0; r < 4; r++) {
                int grow = m0 + wm * 64 + mi * 16 + (lane >> 4) * 4 + r;
                if (grow < M) {
                    float val = fmaxf(acc[mi][ni][r] * s + t, 0.0f);
                    out[(size_t)grow * ldo + gcol] = (f16)val;
                }
            }
        }
    }
}

// ---------------- head: fc1(relu) GEMM with fused fc2 + log_softmax epilogue ----------

__global__ __launch_bounds__(256) void k_gemm_head(
    const f16* __restrict__ A1, int k1, const f16* __restrict__ B1,
    const float* __restrict__ sh,
    const float* __restrict__ w2, const float* __restrict__ b2,
    float* __restrict__ out, int M) {
    __shared__ f16 aT[2][128 * 32];
    __shared__ f16 bT[2][128 * 32];
    __shared__ float smred[128][2][2];
    const int tid = threadIdx.x;
    const int lane = tid & 63;
    const int wid = tid >> 6;
    const int wm = wid >> 1, wn = wid & 1;
    const int m0 = blockIdx.x * 128;
    f32x4 acc[4][4] = {};

    const int srow = tid >> 2;
    const int schunk = (tid & 3) ^ ((tid >> 3) & 3);

    auto stage = [&](int buf, int kk) {
#pragma unroll
        for (int hh = 0; hh < 2; hh++) {
            int r = hh * 64 + srow;
            int gm = m0 + r;
            gm = gm < M ? gm : M - 1;
            gload_lds16(A1 + (size_t)gm * k1 + kk + schunk * 8,
                        (char*)&aT[buf][0] + hh * 4096 + tid * 16);
            gload_lds16(B1 + (size_t)r * k1 + kk + schunk * 8,
                        (char*)&bT[buf][0] + hh * 4096 + tid * 16);
        }
    };

    auto compute = [&](int buf) {
        half8 af[4], bf[4];
#pragma unroll
        for (int mi = 0; mi < 4; mi++) {
            int row = wm * 64 + mi * 16 + (lane & 15);
            int ch = (lane >> 4) ^ ((row >> 1) & 3);
            af[mi] = *(const half8*)((const char*)&aT[buf][0] + row * 64 + ch * 16);
        }
#pragma unroll
        for (int ni = 0; ni < 4; ni++) {
            int row = wn * 64 + ni * 16 + (lane & 15);
            int ch = (lane >> 4) ^ ((row >> 1) & 3);
            bf[ni] = *(const half8*)((const char*)&bT[buf][0] + row * 64 + ch * 16);
        }
#pragma unroll
        for (int mi = 0; mi < 4; mi++)
#pragma unroll
            for (int ni = 0; ni < 4; ni++)
                acc[mi][ni] = __builtin_amdgcn_mfma_f32_16x16x32_f16(af[mi], bf[ni],
                                                                     acc[mi][ni], 0, 0, 0);
    };

    stage(0, 0);
    __syncthreads();
    int cur = 0;
    for (int kk = 32; kk < k1; kk += 32) {
        stage(cur ^ 1, kk);
        compute(cur);
        __syncthreads();
        cur ^= 1;
    }
    compute(cur);

    // fused epilogue: relu(acc + b1) @ w2  -> log_softmax
    float w2c[4][2], shc[4];
#pragma unroll
    for (int ni = 0; ni < 4; ni++) {
        int c = wn * 64 + ni * 16 + (lane & 15);
        w2c[ni][0] = w2[c * 2];
        w2c[ni][1] = w2[c * 2 + 1];
        shc[ni] = sh[c];
    }
#pragma unroll
    for (int mi = 0; mi < 4; mi++) {
#pragma unroll
        for (int r = 0; r < 4; r++) {
            float p0 = 0.0f, p1 = 0.0f;
#pragma unroll
            for (int ni = 0; ni < 4; ni++) {
                float val = fmaxf(acc[mi][ni][r] + shc[ni], 0.0f);
                p0 += val * w2c[ni][0];
                p1 += val * w2c[ni][1];
            }
#pragma unroll
            for (int o = 1; o < 16; o <<= 1) {
                p0 += __shfl_xor(p0, o);
                p1 += __shfl_xor(p1, o);
            }
            if ((lane & 15) == 0) {
                int lrow = wm * 64 + mi * 16 + (lane >> 4) * 4 + r;
                smred[lrow][wn][0] = p0;
                smred[lrow][wn][1] = p1;
            }
        }
    }
    __syncthreads();
    if (tid < 128) {
        int grow = m0 + tid;
        if (grow < M) {
            float l0 = smred[tid][0][0] + smred[tid][1][0] + b2[0];
            float l1 = smred[tid][0][1] + smred[tid][1][1] + b2[1];
            float m = fmaxf(l0, l1);
            float lse = m + logf(expf(l0 - m) + expf(l1 - m));
            out[(size_t)grow * 2] = l0 - lse;
            out[(size_t)grow * 2 + 1] = l1 - lse;
        }
    }
}

// ---------------- launch ----------------

extern "C" void kernel_launch(void* const* d_in, const int* in_sizes, int n_in,
                              void* d_out, int out_size, void* d_ws, size_t ws_size,
                              hipStream_t stream) {
    const float* x     = (const float*)d_in[0];
    const int*   ei    = (const int*)d_in[1];
    const float* wn0   = (const float*)d_in[2];
    const float* wr0   = (const float*)d_in[3];
    const float* b0    = (const float*)d_in[4];
    const float* wn12  = (const float*)d_in[5];
    const float* wr12  = (const float*)d_in[6];
    const float* bvec  = (const float*)d_in[7];
    const float* gamma = (const float*)d_in[8];
    const float* beta  = (const float*)d_in[9];
    const float* mean  = (const float*)d_in[10];
    const float* var   = (const float*)d_in[11];
    const float* w1    = (const float*)d_in[12];
    const float* b1    = (const float*)d_in[13];
    const float* w2    = (const float*)d_in[14];
    const float* b2    = (const float*)d_in[15];
    const int* srcv = ei;
    const int* dstv = ei + N_EDGES;

    char* p = (char*)d_ws;
    auto alloc = [&](size_t bytes) {
        char* r = p;
        p += (bytes + 255) & ~(size_t)255;
        return r;
    };
    int*   deg       = (int*)alloc((size_t)N_NODES * 4);
    int*   row_start = (int*)alloc((size_t)(N_NODES + 1) * 4);
    int*   cursor    = (int*)alloc((size_t)N_NODES * 4);
    float* inv_deg   = (float*)alloc((size_t)N_NODES * 4);
    int*   partials  = (int*)alloc(256 * 4);
    int*   pscan     = (int*)alloc(256 * 4);
    int*   csr       = (int*)alloc((size_t)N_EDGES * 4);
    f16*   Wn0t      = (f16*)alloc(128 * 256 * 2);
    f16*   Wr0t      = (f16*)alloc(128 * 256 * 2);
    f16*   Wn1t      = (f16*)alloc(256 * 256 * 2);
    f16*   Wr1t      = (f16*)alloc(256 * 256 * 2);
    f16*   Wn2t      = (f16*)alloc(256 * 256 * 2);
    f16*   Wr2t      = (f16*)alloc(256 * 256 * 2);
    f16*   W1t       = (f16*)alloc(256 * 128 * 2);
    float* st        = (float*)alloc(4 * 512 * 4);
    f16*   hA        = (f16*)alloc((size_t)N_NODES * 256 * 2);
    f16*   hB        = (f16*)alloc((size_t)N_NODES * 256 * 2);
    f16*   agg       = (f16*)alloc((size_t)N_NODES * 256 * 2);

    hipMemsetAsync(deg, 0, (size_t)N_NODES * 4, stream);
    hipMemsetAsync(cursor, 0, (size_t)N_NODES * 4, stream);

    const int EB = (N_EDGES + 255) / 256;
    const int NBLK = (N_NODES + 255) / 256;

    // fused prep (cvt + weight transposes + BN fold + deg histogram)
    k_prep<<<10784, 256, 0, stream>>>(x, hA, wn0, Wn0t, wr0, Wr0t,
                                      wn12, Wn1t, Wn2t, wr12, Wr1t, Wr2t,
                                      w1, W1t, b0, bvec, gamma, beta, mean, var,
                                      b1, st, dstv, deg);
    k_scan1<<<NBLK, 256, 0, stream>>>(deg, row_start, partials);
    k_scan2<<<1, 256, 0, stream>>>(partials, pscan, NBLK);
    k_scan3<<<NBLK, 256, 0, stream>>>(deg, row_start, pscan, inv_deg);
    k_fill<<<EB, 256, 0, stream>>>(srcv, dstv, row_start, cursor, csr);

    const int AB = (N_NODES + 3) / 4;          // k_agg: 4 nodes/block
    const int GB = (N_NODES + 127) / 128;      // k_gemm: 128 rows/block, full N

    // layer 0
    k_agg<128><<<AB, 256, 0, stream>>>(hA, row_start, csr, inv_deg, agg);
    k_gemm<<<GB, 512, 0, stream>>>(agg, 128, Wn0t, 128, hA, 128, Wr0t, 128,
                                   st + 0, st + 256, hB, 256, N_NODES);
    // layer 1
    k_agg<256><<<AB, 256, 0, stream>>>(hB, row_start, csr, inv_deg, agg);
    k_gemm<<<GB, 512, 0, stream>>>(agg, 256, Wn1t, 256, hB, 256, Wr1t, 256,
                                   st + 512, st + 768, hA, 256, N_NODES);
    // layer 2
    k_agg<256><<<AB, 256, 0, stream>>>(hA, row_start, csr, inv_deg, agg);
    k_gemm<<<GB, 512, 0, stream>>>(agg, 256, Wn2t, 256, hA, 256, Wr2t, 256,
                                   st + 1024, st + 1280, hB, 256, N_NODES);
    // head: fc1 + relu + fc2 + log_softmax fused
    k_gemm_head<<<(N_NODES + 127) / 128, 256, 0, stream>>>(
        hB, 256, W1t, st + 1792, w2, b2, (float*)d_out, N_NODES);
}

// Round 11
// 331.290 us; speedup vs baseline: 1.6013x; 1.0102x over previous
//
#include <hip/hip_runtime.h>
#include <hip/hip_fp16.h>

#define N_NODES 50000
#define N_EDGES 800000
#define DIM_IN 128
#define DIM_H 256

typedef _Float16 f16;
typedef _Float16 half8 __attribute__((ext_vector_type(8)));
typedef _Float16 f16x4 __attribute__((ext_vector_type(4)));
typedef _Float16 f16x2 __attribute__((ext_vector_type(2)));
typedef float f32x4 __attribute__((ext_vector_type(4)));
typedef unsigned int u32;

__device__ __forceinline__ void gload_lds16(const void* g, void* l) {
    __builtin_amdgcn_global_load_lds(
        (const __attribute__((address_space(1))) u32*)g,
        (__attribute__((address_space(3))) u32*)l,
        16, 0, 0);
}

// ---------------- graph build ----------------

__global__ void k_scan1(const int* __restrict__ deg, int* __restrict__ row_start,
                        int* __restrict__ partials) {
    __shared__ int sm[256];
    int t = threadIdx.x;
    int i = blockIdx.x * 256 + t;
    int v = (i < N_NODES) ? deg[i] : 0;
    sm[t] = v;
    __syncthreads();
    for (int ofs = 1; ofs < 256; ofs <<= 1) {
        int add = (t >= ofs) ? sm[t - ofs] : 0;
        __syncthreads();
        sm[t] += add;
        __syncthreads();
    }
    if (i < N_NODES) row_start[i] = sm[t] - v;   // exclusive within block
    if (t == 255) partials[blockIdx.x] = sm[255];
}

// merged scan2+scan3: each block redoes the tiny partials-scan in LDS and
// applies its own exclusive prefix to its 256 row_start entries.
__global__ void k_scan23(int* __restrict__ row_start,
                         const int* __restrict__ partials, int nblk) {
    __shared__ int sm[256];
    int t = threadIdx.x, b = blockIdx.x;
    int v = (t < nblk) ? partials[t] : 0;
    sm[t] = v;
    __syncthreads();
    for (int ofs = 1; ofs < 256; ofs <<= 1) {
        int add = (t >= ofs) ? sm[t - ofs] : 0;
        __syncthreads();
        sm[t] += add;
        __syncthreads();
    }
    int pre = sm[b] - partials[b];   // exclusive prefix for this block
    int i = b * 256 + t;
    if (i < N_NODES) row_start[i] += pre;
    if (b == 0 && t == 0) row_start[N_NODES] = N_EDGES;
}

__global__ void k_fill(const int* __restrict__ src, const int* __restrict__ dst,
                       const int* __restrict__ row_start, int* __restrict__ cursor,
                       int* __restrict__ csr) {
    int i = blockIdx.x * 256 + threadIdx.x;
    if (i < N_EDGES) {
        int d = dst[i];
        int p = atomicAdd(&cursor[d], 1);
        csr[row_start[d] + p] = src[i];
    }
}

// ---------------- fused prep: cvt_x + 7 tcvt + st + deg histogram ----------------

__global__ void k_prep(const float* __restrict__ x, f16* __restrict__ hA,
                       const float* __restrict__ wn0, f16* __restrict__ Wn0t,
                       const float* __restrict__ wr0, f16* __restrict__ Wr0t,
                       const float* __restrict__ wn12, f16* __restrict__ Wn1t,
                       f16* __restrict__ Wn2t,
                       const float* __restrict__ wr12, f16* __restrict__ Wr1t,
                       f16* __restrict__ Wr2t,
                       const float* __restrict__ w1, f16* __restrict__ W1t,
                       const float* __restrict__ b0, const float* __restrict__ bvec,
                       const float* __restrict__ gamma, const float* __restrict__ beta,
                       const float* __restrict__ mean, const float* __restrict__ var,
                       const float* __restrict__ b1, float* __restrict__ st,
                       const int* __restrict__ dst, int* __restrict__ deg) {
    const int t = threadIdx.x;
    int b = blockIdx.x;
    auto tcvt = [&](const float* W, f16* Wt, int K, int NN, int bb) {
        int tt = bb * 256 + t;
        int n = tt / K, k = tt - n * K;
        Wt[tt] = (f16)W[(size_t)k * NN + n];
    };
    if (b < 6250) {
        int i = b * 256 + t;   // < 1.6M exactly
        float4 v = ((const float4*)x)[i];
        f16x4 h = {(f16)v.x, (f16)v.y, (f16)v.z, (f16)v.w};
        *(f16x4*)(hA + (size_t)i * 4) = h;
    } else if (b < 6378) {
        tcvt(wn0, Wn0t, 128, 256, b - 6250);
    } else if (b < 6506) {
        tcvt(wr0, Wr0t, 128, 256, b - 6378);
    } else if (b < 6762) {
        tcvt(wn12, Wn1t, 256, 256, b - 6506);
    } else if (b < 7018) {
        tcvt(wn12 + 65536, Wn2t, 256, 256, b - 6762);
    } else if (b < 7274) {
        tcvt(wr12, Wr1t, 256, 256, b - 7018);
    } else if (b < 7530) {
        tcvt(wr12 + 65536, Wr2t, 256, 256, b - 7274);
    } else if (b < 7658) {
        tcvt(w1, W1t, 256, 128, b - 7530);
    } else if (b == 7658) {
        int c = t;
        for (int layer = 0; layer < 3; layer++) {
            float bias = (layer == 0) ? b0[c] : bvec[(layer - 1) * DIM_H + c];
            float g = gamma[layer * DIM_H + c];
            float be = beta[layer * DIM_H + c];
            float mu = mean[layer * DIM_H + c];
            float va = var[layer * DIM_H + c];
            float s = g * rsqrtf(va + 1e-5f);
            st[layer * 512 + c] = s;
            st[layer * 512 + 256 + c] = (bias - mu) * s + be;
        }
        st[3 * 512 + c] = 1.0f;
        st[3 * 512 + 256 + c] = (c < 128) ? b1[c] : 0.0f;
    } else {
        int i = (b - 7659) * 256 + t;
        if (i < N_EDGES) atomicAdd(&deg[dst[i]], 1);
    }
}

// ---------------- aggregation: one wave per node, 16 gathers in flight ----------------
// 8 waves/block (occupancy probe); inv_deg computed from e1-e0 (array removed).

template <int D>
__global__ void k_agg(const f16* __restrict__ h, const int* __restrict__ row_start,
                      const int* __restrict__ csr, f16* __restrict__ agg) {
    constexpr int V = D / 64;  // halves per lane: 2 or 4
    typedef _Float16 fvec __attribute__((ext_vector_type(V)));
    int wid = threadIdx.x >> 6;
    int lane = threadIdx.x & 63;
    int v = blockIdx.x * 8 + wid;
    if (v >= N_NODES) return;
    int e0 = row_start[v], e1 = row_start[v + 1];
    float acc[V];
#pragma unroll
    for (int j = 0; j < V; j++) acc[j] = 0.0f;

    const int li = lane & 15;
    for (int e = e0; e < e1; e += 16) {
        int ee = e + li;
        int idx = csr[ee < e1 ? ee : e1 - 1];   // coalesced; tail lanes duplicate last
        int rem = e1 - e;                        // wave-uniform
        fvec hv[16];
#pragma unroll
        for (int j = 0; j < 16; j++) {
            int s = __shfl(idx, j);
            hv[j] = *(const fvec*)(h + (size_t)s * D + lane * V);  // 16 loads in flight
        }
#pragma unroll
        for (int j = 0; j < 16; j++) {
            if (j < rem) {  // wave-uniform scalar branch
#pragma unroll
                for (int q = 0; q < V; q++) acc[q] += (float)hv[j][q];
            }
        }
    }

    int d = e1 - e0;
    float sc = 1.0f / (float)(d > 1 ? d : 1);
    fvec o;
#pragma unroll
    for (int j = 0; j < V; j++) o[j] = (f16)(acc[j] * sc);
    *(fvec*)(agg + (size_t)v * D + lane * V) = o;
}

// ---------------- GEMM: C = relu(sc * (A1@B1t^T + A2@B2t^T) + sh) ----------------
// BM=128 x BN=256, 512 threads (8 waves, 2x4), each wave 64x64 (4x4 of 16x16x32).
// K-step 32, double-buffered LDS (48KB -> 3 blocks/CU). Bt[n][k].

__global__ __launch_bounds__(512) void k_gemm(
    const f16* __restrict__ A1, int lda1, const f16* __restrict__ B1, int k1,
    const f16* __restrict__ A2, int lda2, const f16* __restrict__ B2, int k2,
    const float* __restrict__ sc, const float* __restrict__ sh,
    f16* __restrict__ out, int ldo, int M) {
    __shared__ f16 aT[2][128 * 32];
    __shared__ f16 bT[2][256 * 32];
    const int tid = threadIdx.x;
    const int lane = tid & 63;
    const int wid = tid >> 6;
    const int wm = wid >> 2;            // 0..1: row half
    const int wn = wid & 3;             // 0..3: col quarter
    const int m0 = blockIdx.x * 128;
    f32x4 acc[4][4] = {};

    const int srow = tid >> 2;                       // 0..127
    const int schunk = (tid & 3) ^ ((tid >> 3) & 3); // pre-swizzled global chunk
    const int ktot = k1 + k2;

    auto stage = [&](int buf, int kk) {
        const f16 *Ap, *Bp;
        int lda, ldb, kloc;
        if (kk < k1) { Ap = A1; Bp = B1; lda = lda1; ldb = k1; kloc = kk; }
        else         { Ap = A2; Bp = B2; lda = lda2; ldb = k2; kloc = kk - k1; }
        // A: 128 rows x 64B -> 1 gload per thread
        int gm = m0 + srow;
        gm = gm < M ? gm : M - 1;
        gload_lds16(Ap + (size_t)gm * lda + kloc + schunk * 8,
                    (char*)&aT[buf][0] + tid * 16);
        // B: 256 rows x 64B -> 2 gloads per thread
#pragma unroll
        for (int hh = 0; hh < 2; hh++) {
            gload_lds16(Bp + (size_t)(hh * 128 + srow) * ldb + kloc + schunk * 8,
                        (char*)&bT[buf][0] + hh * 8192 + tid * 16);
        }
    };

    auto compute = [&](int buf) {
        half8 af[4], bf[4];
#pragma unroll
        for (int mi = 0; mi < 4; mi++) {
            int row = wm * 64 + mi * 16 + (lane & 15);
            int ch = (lane >> 4) ^ ((row >> 1) & 3);
            af[mi] = *(const half8*)((const char*)&aT[buf][0] + row * 64 + ch * 16);
        }
#pragma unroll
        for (int ni = 0; ni < 4; ni++) {
            int row = wn * 64 + ni * 16 + (lane & 15);
            int ch = (lane >> 4) ^ ((row >> 1) & 3);
            bf[ni] = *(const half8*)((const char*)&bT[buf][0] + row * 64 + ch * 16);
        }
#pragma unroll
        for (int mi = 0; mi < 4; mi++)
#pragma unroll
            for (int ni = 0; ni < 4; ni++)
                acc[mi][ni] = __builtin_amdgcn_mfma_f32_16x16x32_f16(af[mi], bf[ni],
                                                                     acc[mi][ni], 0, 0, 0);
    };

    stage(0, 0);
    __syncthreads();
    int cur = 0;
    for (int kk = 32; kk < ktot; kk += 32) {
        stage(cur ^ 1, kk);
        compute(cur);
        __syncthreads();
        cur ^= 1;
    }
    compute(cur);

#pragma unroll
    for (int mi = 0; mi < 4; mi++) {
#pragma unroll
        for (int ni = 0; ni < 4; ni++) {
            int gcol = wn * 64 + ni * 16 + (lane & 15);
            float s = sc[gcol], t = sh[gcol];
#pragma unroll
            for (int r = 0; r < 4; r++) {
                int grow = m0 + wm * 64 + mi * 16 + (lane >> 4) * 4 + r;
                if (grow < M) {
                    float val = fmaxf(acc[mi][ni][r] * s + t, 0.0f);
                    out[(size_t)grow * ldo + gcol] = (f16)val;
                }
            }
        }
    }
}

// ---------------- head: fc1(relu) GEMM with fused fc2 + log_softmax epilogue ----------

__global__ __launch_bounds__(256) void k_gemm_head(
    const f16* __restrict__ A1, int k1, const f16* __restrict__ B1,
    const float* __restrict__ sh,
    const float* __restrict__ w2, const float* __restrict__ b2,
    float* __restrict__ out, int M) {
    __shared__ f16 aT[2][128 * 32];
    __shared__ f16 bT[2][128 * 32];
    __shared__ float smred[128][2][2];
    const int tid = threadIdx.x;
    const int lane = tid & 63;
    const int wid = tid >> 6;
    const int wm = wid >> 1, wn = wid & 1;
    const int m0 = blockIdx.x * 128;
    f32x4 acc[4][4] = {};

    const int srow = tid >> 2;
    const int schunk = (tid & 3) ^ ((tid >> 3) & 3);

    auto stage = [&](int buf, int kk) {
#pragma unroll
        for (int hh = 0; hh < 2; hh++) {
            int r = hh * 64 + srow;
            int gm = m0 + r;
            gm = gm < M ? gm : M - 1;
            gload_lds16(A1 + (size_t)gm * k1 + kk + schunk * 8,
                        (char*)&aT[buf][0] + hh * 4096 + tid * 16);
            gload_lds16(B1 + (size_t)r * k1 + kk + schunk * 8,
                        (char*)&bT[buf][0] + hh * 4096 + tid * 16);
        }
    };

    auto compute = [&](int buf) {
        half8 af[4], bf[4];
#pragma unroll
        for (int mi = 0; mi < 4; mi++) {
            int row = wm * 64 + mi * 16 + (lane & 15);
            int ch = (lane >> 4) ^ ((row >> 1) & 3);
            af[mi] = *(const half8*)((const char*)&aT[buf][0] + row * 64 + ch * 16);
        }
#pragma unroll
        for (int ni = 0; ni < 4; ni++) {
            int row = wn * 64 + ni * 16 + (lane & 15);
            int ch = (lane >> 4) ^ ((row >> 1) & 3);
            bf[ni] = *(const half8*)((const char*)&bT[buf][0] + row * 64 + ch * 16);
        }
#pragma unroll
        for (int mi = 0; mi < 4; mi++)
#pragma unroll
            for (int ni = 0; ni < 4; ni++)
                acc[mi][ni] = __builtin_amdgcn_mfma_f32_16x16x32_f16(af[mi], bf[ni],
                                                                     acc[mi][ni], 0, 0, 0);
    };

    stage(0, 0);
    __syncthreads();
    int cur = 0;
    for (int kk = 32; kk < k1; kk += 32) {
        stage(cur ^ 1, kk);
        compute(cur);
        __syncthreads();
        cur ^= 1;
    }
    compute(cur);

    // fused epilogue: relu(acc + b1) @ w2  -> log_softmax
    float w2c[4][2], shc[4];
#pragma unroll
    for (int ni = 0; ni < 4; ni++) {
        int c = wn * 64 + ni * 16 + (lane & 15);
        w2c[ni][0] = w2[c * 2];
        w2c[ni][1] = w2[c * 2 + 1];
        shc[ni] = sh[c];
    }
#pragma unroll
    for (int mi = 0; mi < 4; mi++) {
#pragma unroll
        for (int r = 0; r < 4; r++) {
            float p0 = 0.0f, p1 = 0.0f;
#pragma unroll
            for (int ni = 0; ni < 4; ni++) {
                float val = fmaxf(acc[mi][ni][r] + shc[ni], 0.0f);
                p0 += val * w2c[ni][0];
                p1 += val * w2c[ni][1];
            }
#pragma unroll
            for (int o = 1; o < 16; o <<= 1) {
                p0 += __shfl_xor(p0, o);
                p1 += __shfl_xor(p1, o);
            }
            if ((lane & 15) == 0) {
                int lrow = wm * 64 + mi * 16 + (lane >> 4) * 4 + r;
                smred[lrow][wn][0] = p0;
                smred[lrow][wn][1] = p1;
            }
        }
    }
    __syncthreads();
    if (tid < 128) {
        int grow = m0 + tid;
        if (grow < M) {
            float l0 = smred[tid][0][0] + smred[tid][1][0] + b2[0];
            float l1 = smred[tid][0][1] + smred[tid][1][1] + b2[1];
            float m = fmaxf(l0, l1);
            float lse = m + logf(expf(l0 - m) + expf(l1 - m));
            out[(size_t)grow * 2] = l0 - lse;
            out[(size_t)grow * 2 + 1] = l1 - lse;
        }
    }
}

// ---------------- launch ----------------

extern "C" void kernel_launch(void* const* d_in, const int* in_sizes, int n_in,
                              void* d_out, int out_size, void* d_ws, size_t ws_size,
                              hipStream_t stream) {
    const float* x     = (const float*)d_in[0];
    const int*   ei    = (const int*)d_in[1];
    const float* wn0   = (const float*)d_in[2];
    const float* wr0   = (const float*)d_in[3];
    const float* b0    = (const float*)d_in[4];
    const float* wn12  = (const float*)d_in[5];
    const float* wr12  = (const float*)d_in[6];
    const float* bvec  = (const float*)d_in[7];
    const float* gamma = (const float*)d_in[8];
    const float* beta  = (const float*)d_in[9];
    const float* mean  = (const float*)d_in[10];
    const float* var   = (const float*)d_in[11];
    const float* w1    = (const float*)d_in[12];
    const float* b1    = (const float*)d_in[13];
    const float* w2    = (const float*)d_in[14];
    const float* b2    = (const float*)d_in[15];
    const int* srcv = ei;
    const int* dstv = ei + N_EDGES;

    char* p = (char*)d_ws;
    auto alloc = [&](size_t bytes) {
        char* r = p;
        p += (bytes + 255) & ~(size_t)255;
        return r;
    };
    int*   deg       = (int*)alloc((size_t)N_NODES * 4);
    int*   cursor    = (int*)alloc((size_t)N_NODES * 4);   // contiguous with deg
    int*   row_start = (int*)alloc((size_t)(N_NODES + 1) * 4);
    int*   partials  = (int*)alloc(256 * 4);
    int*   csr       = (int*)alloc((size_t)N_EDGES * 4);
    f16*   Wn0t      = (f16*)alloc(128 * 256 * 2);
    f16*   Wr0t      = (f16*)alloc(128 * 256 * 2);
    f16*   Wn1t      = (f16*)alloc(256 * 256 * 2);
    f16*   Wr1t      = (f16*)alloc(256 * 256 * 2);
    f16*   Wn2t      = (f16*)alloc(256 * 256 * 2);
    f16*   Wr2t      = (f16*)alloc(256 * 256 * 2);
    f16*   W1t       = (f16*)alloc(256 * 128 * 2);
    float* st        = (float*)alloc(4 * 512 * 4);
    f16*   hA        = (f16*)alloc((size_t)N_NODES * 256 * 2);
    f16*   hB        = (f16*)alloc((size_t)N_NODES * 256 * 2);
    f16*   agg       = (f16*)alloc((size_t)N_NODES * 256 * 2);

    // one memset covers deg + pad + cursor (contiguous allocations)
    hipMemsetAsync(deg, 0, (size_t)((char*)cursor - (char*)deg) + (size_t)N_NODES * 4,
                   stream);

    const int EB = (N_EDGES + 255) / 256;
    const int NBLK = (N_NODES + 255) / 256;

    // fused prep (cvt + weight transposes + BN fold + deg histogram)
    k_prep<<<10784, 256, 0, stream>>>(x, hA, wn0, Wn0t, wr0, Wr0t,
                                      wn12, Wn1t, Wn2t, wr12, Wr1t, Wr2t,
                                      w1, W1t, b0, bvec, gamma, beta, mean, var,
                                      b1, st, dstv, deg);
    k_scan1<<<NBLK, 256, 0, stream>>>(deg, row_start, partials);
    k_scan23<<<NBLK, 256, 0, stream>>>(row_start, partials, NBLK);
    k_fill<<<EB, 256, 0, stream>>>(srcv, dstv, row_start, cursor, csr);

    const int AB = (N_NODES + 7) / 8;          // k_agg: 8 nodes/block (8 waves)
    const int GB = (N_NODES + 127) / 128;      // k_gemm: 128 rows/block, full N

    // layer 0
    k_agg<128><<<AB, 512, 0, stream>>>(hA, row_start, csr, agg);
    k_gemm<<<GB, 512, 0, stream>>>(agg, 128, Wn0t, 128, hA, 128, Wr0t, 128,
                                   st + 0, st + 256, hB, 256, N_NODES);
    // layer 1
    k_agg<256><<<AB, 512, 0, stream>>>(hB, row_start, csr, agg);
    k_gemm<<<GB, 512, 0, stream>>>(agg, 256, Wn1t, 256, hB, 256, Wr1t, 256,
                                   st + 512, st + 768, hA, 256, N_NODES);
    // layer 2
    k_agg<256><<<AB, 512, 0, stream>>>(hA, row_start, csr, agg);
    k_gemm<<<GB, 512, 0, stream>>>(agg, 256, Wn2t, 256, hA, 256, Wr2t, 256,
                                   st + 1024, st + 1280, hB, 256, N_NODES);
    // head: fc1 + relu + fc2 + log_softmax fused
    k_gemm_head<<<(N_NODES + 127) / 128, 256, 0, stream>>>(
        hB, 256, W1t, st + 1792, w2, b2, (float*)d_out, N_NODES);
}

// Round 12
// 322.433 us; speedup vs baseline: 1.6453x; 1.0275x over previous
//
#include <hip/hip_runtime.h>
#include <hip/hip_fp16.h>

#define N_NODES 50000
#define N_EDGES 800000
#define DIM_IN 128
#define DIM_H 256

typedef _Float16 f16;
typedef _Float16 half8 __attribute__((ext_vector_type(8)));
typedef _Float16 f16x4 __attribute__((ext_vector_type(4)));
typedef _Float16 f16x2 __attribute__((ext_vector_type(2)));
typedef float f32x4 __attribute__((ext_vector_type(4)));
typedef unsigned int u32;

__device__ __forceinline__ void gload_lds16(const void* g, void* l) {
    __builtin_amdgcn_global_load_lds(
        (const __attribute__((address_space(1))) u32*)g,
        (__attribute__((address_space(3))) u32*)l,
        16, 0, 0);
}

// ---------------- graph build ----------------

__global__ void k_scan1(const int* __restrict__ deg, int* __restrict__ row_start,
                        int* __restrict__ partials) {
    __shared__ int sm[256];
    int t = threadIdx.x;
    int i = blockIdx.x * 256 + t;
    int v = (i < N_NODES) ? deg[i] : 0;
    sm[t] = v;
    __syncthreads();
    for (int ofs = 1; ofs < 256; ofs <<= 1) {
        int add = (t >= ofs) ? sm[t - ofs] : 0;
        __syncthreads();
        sm[t] += add;
        __syncthreads();
    }
    if (i < N_NODES) row_start[i] = sm[t] - v;   // exclusive within block
    if (t == 255) partials[blockIdx.x] = sm[255];
}

// merged scan2+scan3: each block redoes the tiny partials-scan in LDS and
// applies its own exclusive prefix to its 256 row_start entries.
__global__ void k_scan23(int* __restrict__ row_start,
                         const int* __restrict__ partials, int nblk) {
    __shared__ int sm[256];
    int t = threadIdx.x, b = blockIdx.x;
    int v = (t < nblk) ? partials[t] : 0;
    sm[t] = v;
    __syncthreads();
    for (int ofs = 1; ofs < 256; ofs <<= 1) {
        int add = (t >= ofs) ? sm[t - ofs] : 0;
        __syncthreads();
        sm[t] += add;
        __syncthreads();
    }
    int pre = sm[b] - partials[b];   // exclusive prefix for this block
    int i = b * 256 + t;
    if (i < N_NODES) row_start[i] += pre;
    if (b == 0 && t == 0) row_start[N_NODES] = N_EDGES;
}

__global__ void k_fill(const int* __restrict__ src, const int* __restrict__ dst,
                       const int* __restrict__ row_start, int* __restrict__ cursor,
                       int* __restrict__ csr) {
    int i = blockIdx.x * 256 + threadIdx.x;
    if (i < N_EDGES) {
        int d = dst[i];
        int p = atomicAdd(&cursor[d], 1);
        csr[row_start[d] + p] = src[i];
    }
}

// ---------------- fused prep: cvt_x + 7 tcvt + st + deg histogram ----------------

__global__ void k_prep(const float* __restrict__ x, f16* __restrict__ hA,
                       const float* __restrict__ wn0, f16* __restrict__ Wn0t,
                       const float* __restrict__ wr0, f16* __restrict__ Wr0t,
                       const float* __restrict__ wn12, f16* __restrict__ Wn1t,
                       f16* __restrict__ Wn2t,
                       const float* __restrict__ wr12, f16* __restrict__ Wr1t,
                       f16* __restrict__ Wr2t,
                       const float* __restrict__ w1, f16* __restrict__ W1t,
                       const float* __restrict__ b0, const float* __restrict__ bvec,
                       const float* __restrict__ gamma, const float* __restrict__ beta,
                       const float* __restrict__ mean, const float* __restrict__ var,
                       const float* __restrict__ b1, float* __restrict__ st,
                       const int* __restrict__ dst, int* __restrict__ deg) {
    const int t = threadIdx.x;
    int b = blockIdx.x;
    auto tcvt = [&](const float* W, f16* Wt, int K, int NN, int bb) {
        int tt = bb * 256 + t;
        int n = tt / K, k = tt - n * K;
        Wt[tt] = (f16)W[(size_t)k * NN + n];
    };
    if (b < 6250) {
        int i = b * 256 + t;   // < 1.6M exactly
        float4 v = ((const float4*)x)[i];
        f16x4 h = {(f16)v.x, (f16)v.y, (f16)v.z, (f16)v.w};
        *(f16x4*)(hA + (size_t)i * 4) = h;
    } else if (b < 6378) {
        tcvt(wn0, Wn0t, 128, 256, b - 6250);
    } else if (b < 6506) {
        tcvt(wr0, Wr0t, 128, 256, b - 6378);
    } else if (b < 6762) {
        tcvt(wn12, Wn1t, 256, 256, b - 6506);
    } else if (b < 7018) {
        tcvt(wn12 + 65536, Wn2t, 256, 256, b - 6762);
    } else if (b < 7274) {
        tcvt(wr12, Wr1t, 256, 256, b - 7018);
    } else if (b < 7530) {
        tcvt(wr12 + 65536, Wr2t, 256, 256, b - 7274);
    } else if (b < 7658) {
        tcvt(w1, W1t, 256, 128, b - 7530);
    } else if (b == 7658) {
        int c = t;
        for (int layer = 0; layer < 3; layer++) {
            float bias = (layer == 0) ? b0[c] : bvec[(layer - 1) * DIM_H + c];
            float g = gamma[layer * DIM_H + c];
            float be = beta[layer * DIM_H + c];
            float mu = mean[layer * DIM_H + c];
            float va = var[layer * DIM_H + c];
            float s = g * rsqrtf(va + 1e-5f);
            st[layer * 512 + c] = s;
            st[layer * 512 + 256 + c] = (bias - mu) * s + be;
        }
        st[3 * 512 + c] = 1.0f;
        st[3 * 512 + 256 + c] = (c < 128) ? b1[c] : 0.0f;
    } else {
        int i = (b - 7659) * 256 + t;
        if (i < N_EDGES) atomicAdd(&deg[dst[i]], 1);
    }
}

// ---------------- aggregation: one wave per node, 16 gathers in flight (proven) ----
// 4 waves/block (256 thr) — R11's 8-wave probe regressed (occupancy 50->41%).

template <int D>
__global__ void k_agg(const f16* __restrict__ h, const int* __restrict__ row_start,
                      const int* __restrict__ csr, f16* __restrict__ agg) {
    constexpr int V = D / 64;  // halves per lane: 2 or 4
    typedef _Float16 fvec __attribute__((ext_vector_type(V)));
    int wid = threadIdx.x >> 6;
    int lane = threadIdx.x & 63;
    int v = blockIdx.x * 4 + wid;
    if (v >= N_NODES) return;
    int e0 = row_start[v], e1 = row_start[v + 1];
    float acc[V];
#pragma unroll
    for (int j = 0; j < V; j++) acc[j] = 0.0f;

    const int li = lane & 15;
    for (int e = e0; e < e1; e += 16) {
        int ee = e + li;
        int idx = csr[ee < e1 ? ee : e1 - 1];   // coalesced; tail lanes duplicate last
        int rem = e1 - e;                        // wave-uniform
        fvec hv[16];
#pragma unroll
        for (int j = 0; j < 16; j++) {
            int s = __shfl(idx, j);
            hv[j] = *(const fvec*)(h + (size_t)s * D + lane * V);  // 16 loads in flight
        }
#pragma unroll
        for (int j = 0; j < 16; j++) {
            if (j < rem) {  // wave-uniform scalar branch
#pragma unroll
                for (int q = 0; q < V; q++) acc[q] += (float)hv[j][q];
            }
        }
    }

    int d = e1 - e0;
    float sc = 1.0f / (float)(d > 1 ? d : 1);
    fvec o;
#pragma unroll
    for (int j = 0; j < V; j++) o[j] = (f16)(acc[j] * sc);
    *(fvec*)(agg + (size_t)v * D + lane * V) = o;
}

// ---------------- GEMM: C = relu(sc * (A1@B1t^T + A2@B2t^T) + sh) ----------------
// BM=128 x BN=256, 512 threads (8 waves, 2x4), each wave 64x64 (4x4 of 16x16x32).
// K-step 32, double-buffered LDS (48KB -> 3 blocks/CU). Bt[n][k].

__global__ __launch_bounds__(512) void k_gemm(
    const f16* __restrict__ A1, int lda1, const f16* __restrict__ B1, int k1,
    const f16* __restrict__ A2, int lda2, const f16* __restrict__ B2, int k2,
    const float* __restrict__ sc, const float* __restrict__ sh,
    f16* __restrict__ out, int ldo, int M) {
    __shared__ f16 aT[2][128 * 32];
    __shared__ f16 bT[2][256 * 32];
    const int tid = threadIdx.x;
    const int lane = tid & 63;
    const int wid = tid >> 6;
    const int wm = wid >> 2;            // 0..1: row half
    const int wn = wid & 3;             // 0..3: col quarter
    const int m0 = blockIdx.x * 128;
    f32x4 acc[4][4] = {};

    const int srow = tid >> 2;                       // 0..127
    const int schunk = (tid & 3) ^ ((tid >> 3) & 3); // pre-swizzled global chunk
    const int ktot = k1 + k2;

    auto stage = [&](int buf, int kk) {
        const f16 *Ap, *Bp;
        int lda, ldb, kloc;
        if (kk < k1) { Ap = A1; Bp = B1; lda = lda1; ldb = k1; kloc = kk; }
        else         { Ap = A2; Bp = B2; lda = lda2; ldb = k2; kloc = kk - k1; }
        // A: 128 rows x 64B -> 1 gload per thread
        int gm = m0 + srow;
        gm = gm < M ? gm : M - 1;
        gload_lds16(Ap + (size_t)gm * lda + kloc + schunk * 8,
                    (char*)&aT[buf][0] + tid * 16);
        // B: 256 rows x 64B -> 2 gloads per thread
#pragma unroll
        for (int hh = 0; hh < 2; hh++) {
            gload_lds16(Bp + (size_t)(hh * 128 + srow) * ldb + kloc + schunk * 8,
                        (char*)&bT[buf][0] + hh * 8192 + tid * 16);
        }
    };

    auto compute = [&](int buf) {
        half8 af[4], bf[4];
#pragma unroll
        for (int mi = 0; mi < 4; mi++) {
            int row = wm * 64 + mi * 16 + (lane & 15);
            int ch = (lane >> 4) ^ ((row >> 1) & 3);
            af[mi] = *(const half8*)((const char*)&aT[buf][0] + row * 64 + ch * 16);
        }
#pragma unroll
        for (int ni = 0; ni < 4; ni++) {
            int row = wn * 64 + ni * 16 + (lane & 15);
            int ch = (lane >> 4) ^ ((row >> 1) & 3);
            bf[ni] = *(const half8*)((const char*)&bT[buf][0] + row * 64 + ch * 16);
        }
#pragma unroll
        for (int mi = 0; mi < 4; mi++)
#pragma unroll
            for (int ni = 0; ni < 4; ni++)
                acc[mi][ni] = __builtin_amdgcn_mfma_f32_16x16x32_f16(af[mi], bf[ni],
                                                                     acc[mi][ni], 0, 0, 0);
    };

    stage(0, 0);
    __syncthreads();
    int cur = 0;
    for (int kk = 32; kk < ktot; kk += 32) {
        stage(cur ^ 1, kk);
        compute(cur);
        __syncthreads();
        cur ^= 1;
    }
    compute(cur);

#pragma unroll
    for (int mi = 0; mi < 4; mi++) {
#pragma unroll
        for (int ni = 0; ni < 4; ni++) {
            int gcol = wn * 64 + ni * 16 + (lane & 15);
            float s = sc[gcol], t = sh[gcol];
#pragma unroll
            for (int r = 0; r < 4; r++) {
                int grow = m0 + wm * 64 + mi * 16 + (lane >> 4) * 4 + r;
                if (grow < M) {
                    float val = fmaxf(acc[mi][ni][r] * s + t, 0.0f);
                    out[(size_t)grow * ldo + gcol] = (f16)val;
                }
            }
        }
    }
}

// ---------------- head: fc1(relu) GEMM with fused fc2 + log_softmax epilogue ----------

__global__ __launch_bounds__(256) void k_gemm_head(
    const f16* __restrict__ A1, int k1, const f16* __restrict__ B1,
    const float* __restrict__ sh,
    const float* __restrict__ w2, const float* __restrict__ b2,
    float* __restrict__ out, int M) {
    __shared__ f16 aT[2][128 * 32];
    __shared__ f16 bT[2][128 * 32];
    __shared__ float smred[128][2][2];
    const int tid = threadIdx.x;
    const int lane = tid & 63;
    const int wid = tid >> 6;
    const int wm = wid >> 1, wn = wid & 1;
    const int m0 = blockIdx.x * 128;
    f32x4 acc[4][4] = {};

    const int srow = tid >> 2;
    const int schunk = (tid & 3) ^ ((tid >> 3) & 3);

    auto stage = [&](int buf, int kk) {
#pragma unroll
        for (int hh = 0; hh < 2; hh++) {
            int r = hh * 64 + srow;
            int gm = m0 + r;
            gm = gm < M ? gm : M - 1;
            gload_lds16(A1 + (size_t)gm * k1 + kk + schunk * 8,
                        (char*)&aT[buf][0] + hh * 4096 + tid * 16);
            gload_lds16(B1 + (size_t)r * k1 + kk + schunk * 8,
                        (char*)&bT[buf][0] + hh * 4096 + tid * 16);
        }
    };

    auto compute = [&](int buf) {
        half8 af[4], bf[4];
#pragma unroll
        for (int mi = 0; mi < 4; mi++) {
            int row = wm * 64 + mi * 16 + (lane & 15);
            int ch = (lane >> 4) ^ ((row >> 1) & 3);
            af[mi] = *(const half8*)((const char*)&aT[buf][0] + row * 64 + ch * 16);
        }
#pragma unroll
        for (int ni = 0; ni < 4; ni++) {
            int row = wn * 64 + ni * 16 + (lane & 15);
            int ch = (lane >> 4) ^ ((row >> 1) & 3);
            bf[ni] = *(const half8*)((const char*)&bT[buf][0] + row * 64 + ch * 16);
        }
#pragma unroll
        for (int mi = 0; mi < 4; mi++)
#pragma unroll
            for (int ni = 0; ni < 4; ni++)
                acc[mi][ni] = __builtin_amdgcn_mfma_f32_16x16x32_f16(af[mi], bf[ni],
                                                                     acc[mi][ni], 0, 0, 0);
    };

    stage(0, 0);
    __syncthreads();
    int cur = 0;
    for (int kk = 32; kk < k1; kk += 32) {
        stage(cur ^ 1, kk);
        compute(cur);
        __syncthreads();
        cur ^= 1;
    }
    compute(cur);

    // fused epilogue: relu(acc + b1) @ w2  -> log_softmax
    float w2c[4][2], shc[4];
#pragma unroll
    for (int ni = 0; ni < 4; ni++) {
        int c = wn * 64 + ni * 16 + (lane & 15);
        w2c[ni][0] = w2[c * 2];
        w2c[ni][1] = w2[c * 2 + 1];
        shc[ni] = sh[c];
    }
#pragma unroll
    for (int mi = 0; mi < 4; mi++) {
#pragma unroll
        for (int r = 0; r < 4; r++) {
            float p0 = 0.0f, p1 = 0.0f;
#pragma unroll
            for (int ni = 0; ni < 4; ni++) {
                float val = fmaxf(acc[mi][ni][r] + shc[ni], 0.0f);
                p0 += val * w2c[ni][0];
                p1 += val * w2c[ni][1];
            }
#pragma unroll
            for (int o = 1; o < 16; o <<= 1) {
                p0 += __shfl_xor(p0, o);
                p1 += __shfl_xor(p1, o);
            }
            if ((lane & 15) == 0) {
                int lrow = wm * 64 + mi * 16 + (lane >> 4) * 4 + r;
                smred[lrow][wn][0] = p0;
                smred[lrow][wn][1] = p1;
            }
        }
    }
    __syncthreads();
    if (tid < 128) {
        int grow = m0 + tid;
        if (grow < M) {
            float l0 = smred[tid][0][0] + smred[tid][1][0] + b2[0];
            float l1 = smred[tid][0][1] + smred[tid][1][1] + b2[1];
            float m = fmaxf(l0, l1);
            float lse = m + logf(expf(l0 - m) + expf(l1 - m));
            out[(size_t)grow * 2] = l0 - lse;
            out[(size_t)grow * 2 + 1] = l1 - lse;
        }
    }
}

// ---------------- launch ----------------

extern "C" void kernel_launch(void* const* d_in, const int* in_sizes, int n_in,
                              void* d_out, int out_size, void* d_ws, size_t ws_size,
                              hipStream_t stream) {
    const float* x     = (const float*)d_in[0];
    const int*   ei    = (const int*)d_in[1];
    const float* wn0   = (const float*)d_in[2];
    const float* wr0   = (const float*)d_in[3];
    const float* b0    = (const float*)d_in[4];
    const float* wn12  = (const float*)d_in[5];
    const float* wr12  = (const float*)d_in[6];
    const float* bvec  = (const float*)d_in[7];
    const float* gamma = (const float*)d_in[8];
    const float* beta  = (const float*)d_in[9];
    const float* mean  = (const float*)d_in[10];
    const float* var   = (const float*)d_in[11];
    const float* w1    = (const float*)d_in[12];
    const float* b1    = (const float*)d_in[13];
    const float* w2    = (const float*)d_in[14];
    const float* b2    = (const float*)d_in[15];
    const int* srcv = ei;
    const int* dstv = ei + N_EDGES;

    char* p = (char*)d_ws;
    auto alloc = [&](size_t bytes) {
        char* r = p;
        p += (bytes + 255) & ~(size_t)255;
        return r;
    };
    int*   deg       = (int*)alloc((size_t)N_NODES * 4);
    int*   cursor    = (int*)alloc((size_t)N_NODES * 4);   // contiguous with deg
    int*   row_start = (int*)alloc((size_t)(N_NODES + 1) * 4);
    int*   partials  = (int*)alloc(256 * 4);
    int*   csr       = (int*)alloc((size_t)N_EDGES * 4);
    f16*   Wn0t      = (f16*)alloc(128 * 256 * 2);
    f16*   Wr0t      = (f16*)alloc(128 * 256 * 2);
    f16*   Wn1t      = (f16*)alloc(256 * 256 * 2);
    f16*   Wr1t      = (f16*)alloc(256 * 256 * 2);
    f16*   Wn2t      = (f16*)alloc(256 * 256 * 2);
    f16*   Wr2t      = (f16*)alloc(256 * 256 * 2);
    f16*   W1t       = (f16*)alloc(256 * 128 * 2);
    float* st        = (float*)alloc(4 * 512 * 4);
    f16*   hA        = (f16*)alloc((size_t)N_NODES * 256 * 2);
    f16*   hB        = (f16*)alloc((size_t)N_NODES * 256 * 2);
    f16*   agg       = (f16*)alloc((size_t)N_NODES * 256 * 2);

    // one memset covers deg + pad + cursor (contiguous allocations)
    hipMemsetAsync(deg, 0, (size_t)((char*)cursor - (char*)deg) + (size_t)N_NODES * 4,
                   stream);

    const int EB = (N_EDGES + 255) / 256;
    const int NBLK = (N_NODES + 255) / 256;

    // fused prep (cvt + weight transposes + BN fold + deg histogram)
    k_prep<<<10784, 256, 0, stream>>>(x, hA, wn0, Wn0t, wr0, Wr0t,
                                      wn12, Wn1t, Wn2t, wr12, Wr1t, Wr2t,
                                      w1, W1t, b0, bvec, gamma, beta, mean, var,
                                      b1, st, dstv, deg);
    k_scan1<<<NBLK, 256, 0, stream>>>(deg, row_start, partials);
    k_scan23<<<NBLK, 256, 0, stream>>>(row_start, partials, NBLK);
    k_fill<<<EB, 256, 0, stream>>>(srcv, dstv, row_start, cursor, csr);

    const int AB = (N_NODES + 3) / 4;          // k_agg: 4 nodes/block (4 waves)
    const int GB = (N_NODES + 127) / 128;      // k_gemm: 128 rows/block, full N

    // layer 0
    k_agg<128><<<AB, 256, 0, stream>>>(hA, row_start, csr, agg);
    k_gemm<<<GB, 512, 0, stream>>>(agg, 128, Wn0t, 128, hA, 128, Wr0t, 128,
                                   st + 0, st + 256, hB, 256, N_NODES);
    // layer 1
    k_agg<256><<<AB, 256, 0, stream>>>(hB, row_start, csr, agg);
    k_gemm<<<GB, 512, 0, stream>>>(agg, 256, Wn1t, 256, hB, 256, Wr1t, 256,
                                   st + 512, st + 768, hA, 256, N_NODES);
    // layer 2
    k_agg<256><<<AB, 256, 0, stream>>>(hA, row_start, csr, agg);
    k_gemm<<<GB, 512, 0, stream>>>(agg, 256, Wn2t, 256, hA, 256, Wr2t, 256,
                                   st + 1024, st + 1280, hB, 256, N_NODES);
    // head: fc1 + relu + fc2 + log_softmax fused
    k_gemm_head<<<(N_NODES + 127) / 128, 256, 0, stream>>>(
        hB, 256, W1t, st + 1792, w2, b2, (float*)d_out, N_NODES);
}